// Round 1
// baseline (3628.225 us; speedup 1.0000x reference)
//
#include <hip/hip_runtime.h>

// Problem constants
#define SS 128
#define BB 32
#define DD 512
#define HH 512
#define VV 8000
#define VPAD 8064   // 63*128, padded N for projection tiles

typedef __bf16 bf16_t;
typedef __bf16 bf16x8 __attribute__((ext_vector_type(8)));
typedef float  floatx4 __attribute__((ext_vector_type(4)));

__device__ __forceinline__ float sigmoidf_(float x) { return 1.0f / (1.0f + expf(-x)); }

// ---------------- prep: fp32 -> bf16 hi/lo splits ----------------

__global__ __launch_bounds__(256)
void prep_x(const float* __restrict__ x, bf16_t* __restrict__ xh, bf16_t* __restrict__ xl) {
    int i = blockIdx.x * 256 + threadIdx.x;   // SS*BB*DD = 2097152 exact
    float v = x[i];
    bf16_t h = (bf16_t)v;
    xh[i] = h;
    xl[i] = (bf16_t)(v - (float)h);
}

// Wcat[d][l][row(2048)][k(1024)] = k<512 ? W_ih[d][l][row][k] : W_hh[d][l][row][k-512]
__global__ __launch_bounds__(256)
void prep_w(const float* __restrict__ Wf_ih, const float* __restrict__ Wf_hh,
            const float* __restrict__ Wb_ih, const float* __restrict__ Wb_hh,
            bf16_t* __restrict__ Wch, bf16_t* __restrict__ Wcl) {
    int i = blockIdx.x * 256 + threadIdx.x;   // 2*2*2048*1024 = 8388608 exact
    int k   = i & 1023;
    int row = (i >> 10) & 2047;
    int l   = (i >> 21) & 1;
    int d   = (i >> 22) & 1;
    const float* Wih = d ? Wb_ih : Wf_ih;
    const float* Whh = d ? Wb_hh : Wf_hh;
    float v = (k < 512) ? Wih[(size_t)(l * 2048 + row) * 512 + k]
                        : Whh[(size_t)(l * 2048 + row) * 512 + (k - 512)];
    bf16_t h = (bf16_t)v;
    Wch[i] = h;
    Wcl[i] = (bf16_t)(v - (float)h);
}

// Projection weights, plain bf16, rows padded [8000 -> 8064) with zeros
__global__ __launch_bounds__(256)
void prep_wp(const float* __restrict__ Wf, const float* __restrict__ Wb, bf16_t* __restrict__ Wp) {
    int i = blockIdx.x * 256 + threadIdx.x;   // 2*8064*512 = 8257536 exact
    int k   = i & 511;
    int rd  = i >> 9;          // d*8064 + row
    int row = rd % 8064;
    int d   = rd / 8064;
    const float* W = d ? Wb : Wf;
    Wp[i] = (row < VV) ? (bf16_t)W[(size_t)row * 512 + k] : (bf16_t)0.0f;
}

// ---------------- LSTM round ----------------
// Round r: layer0 processes t=r (if r<128), layer1 processes t=r-1 (if r>=1).
// h states double-buffered by round parity (write phase r&1, read phase (r+1)&1).
// Grid (32,2,2): blockIdx.x = 16-col h slice, .y = dir, .z = layer. 512 threads:
// wave w: gate g=w&3, k-half kh=w>>2 (kh0 = input half, kh1 = recurrent half).
// Split-bf16 (3-term) MFMA for ~fp32 accuracy.
__global__ __launch_bounds__(512)
void lstm_round(const bf16_t* __restrict__ x_hi, const bf16_t* __restrict__ x_lo,
                const bf16_t* __restrict__ Wch, const bf16_t* __restrict__ Wcl,
                const float* __restrict__ bf_ih, const float* __restrict__ bf_hh,
                const float* __restrict__ bb_ih, const float* __restrict__ bb_hh,
                bf16_t* __restrict__ h_hi, bf16_t* __restrict__ h_lo,
                float* __restrict__ c_st, bf16_t* __restrict__ hout, int r)
{
    const int s = blockIdx.x;   // 0..31
    const int d = blockIdx.y;
    const int l = blockIdx.z;
    if (l == 0 && r >= SS) return;
    if (l == 1 && r == 0) return;
    const int t   = (l == 0) ? r : (r - 1);
    const int t_x = d ? (SS - 1 - t) : t;     // x index / output time index
    const int p_r = (r + 1) & 1;
    const int p_w = r & 1;

    const int tid  = threadIdx.x;
    const int lane = tid & 63;
    const int wv   = tid >> 6;     // 0..7
    const int g    = wv & 3;       // gate: 0=i 1=f 2=g 3=o
    const int kh   = wv >> 2;      // k-half
    const int lrow = lane & 15;
    const int quad = lane >> 4;
    const int n0   = s * 16;

    // A operand for this k-half (rows are batch, stride 512)
    const bf16_t *Ah, *Al;
    if (kh == 0) {
        if (l == 0) { Ah = x_hi + (size_t)t_x * BB * DD; Al = x_lo + (size_t)t_x * BB * DD; }
        else        { Ah = h_hi + (size_t)((d * 2 + 0) * 2 + p_r) * (BB * HH);
                      Al = h_lo + (size_t)((d * 2 + 0) * 2 + p_r) * (BB * HH); }
    } else {
        Ah = h_hi + (size_t)((d * 2 + l) * 2 + p_r) * (BB * HH);
        Al = h_lo + (size_t)((d * 2 + l) * 2 + p_r) * (BB * HH);
    }

    const int wrow = g * 512 + n0 + lrow;   // weight row for this lane (B-frag n = lane&15)
    const bf16_t* wph = Wch + (size_t)((d * 2 + l) * 2048 + wrow) * 1024 + kh * 512 + quad * 8;
    const bf16_t* wpl = Wcl + (size_t)((d * 2 + l) * 2048 + wrow) * 1024 + kh * 512 + quad * 8;

    const bf16_t* a0h = Ah + (size_t)lrow * HH + quad * 8;        // m-tile 0 (b 0..15)
    const bf16_t* a0l = Al + (size_t)lrow * HH + quad * 8;
    const bf16_t* a1h = Ah + (size_t)(16 + lrow) * HH + quad * 8; // m-tile 1 (b 16..31)
    const bf16_t* a1l = Al + (size_t)(16 + lrow) * HH + quad * 8;

    floatx4 acc0 = {0.f, 0.f, 0.f, 0.f};
    floatx4 acc1 = {0.f, 0.f, 0.f, 0.f};
#pragma unroll 4
    for (int ks = 0; ks < 16; ++ks) {
        const int ko = ks * 32;
        bf16x8 bh = *(const bf16x8*)(wph + ko);
        bf16x8 bl = *(const bf16x8*)(wpl + ko);
        bf16x8 vh0 = *(const bf16x8*)(a0h + ko);
        bf16x8 vl0 = *(const bf16x8*)(a0l + ko);
        bf16x8 vh1 = *(const bf16x8*)(a1h + ko);
        bf16x8 vl1 = *(const bf16x8*)(a1l + ko);
        acc0 = __builtin_amdgcn_mfma_f32_16x16x32_bf16(vh0, bh, acc0, 0, 0, 0);
        acc0 = __builtin_amdgcn_mfma_f32_16x16x32_bf16(vh0, bl, acc0, 0, 0, 0);
        acc0 = __builtin_amdgcn_mfma_f32_16x16x32_bf16(vl0, bh, acc0, 0, 0, 0);
        acc1 = __builtin_amdgcn_mfma_f32_16x16x32_bf16(vh1, bh, acc1, 0, 0, 0);
        acc1 = __builtin_amdgcn_mfma_f32_16x16x32_bf16(vh1, bl, acc1, 0, 0, 0);
        acc1 = __builtin_amdgcn_mfma_f32_16x16x32_bf16(vl1, bh, acc1, 0, 0, 0);
    }

    // C-frag: D[m=(quad*4+reg)][n=lane&15] -> gates to LDS, combine k-halves + 4 gates
    __shared__ float lds_g[2][4][BB][17];
#pragma unroll
    for (int rg = 0; rg < 4; ++rg) {
        lds_g[kh][g][quad * 4 + rg][lrow]      = acc0[rg];
        lds_g[kh][g][16 + quad * 4 + rg][lrow] = acc1[rg];
    }
    __syncthreads();

    {   // 512 outputs (32 b x 16 cols), one per thread
        const int b   = tid >> 4;
        const int c   = tid & 15;
        const int col = n0 + c;
        const float* bih = (d ? bb_ih : bf_ih) + l * 2048;
        const float* bhh = (d ? bb_hh : bf_hh) + l * 2048;
        float iv = lds_g[0][0][b][c] + lds_g[1][0][b][c] + bih[col]         + bhh[col];
        float fv = lds_g[0][1][b][c] + lds_g[1][1][b][c] + bih[512 + col]   + bhh[512 + col];
        float gv = lds_g[0][2][b][c] + lds_g[1][2][b][c] + bih[1024 + col]  + bhh[1024 + col];
        float ov = lds_g[0][3][b][c] + lds_g[1][3][b][c] + bih[1536 + col]  + bhh[1536 + col];
        float* cp = c_st + (size_t)((d * 2 + l) * BB + b) * HH + col;
        float co = *cp;
        float cn = sigmoidf_(fv) * co + sigmoidf_(iv) * tanhf(gv);
        float hn = sigmoidf_(ov) * tanhf(cn);
        *cp = cn;
        bf16_t hh = (bf16_t)hn;
        bf16_t hl = (bf16_t)(hn - (float)hh);
        const size_t hoff = (size_t)((d * 2 + l) * 2 + p_w) * (BB * HH) + (size_t)b * HH + col;
        h_hi[hoff] = hh;
        h_lo[hoff] = hl;
        if (l == 1)  // top-layer h -> projection input, time index t_x for both dirs
            hout[((size_t)(d * SS + t_x) * BB + b) * HH + col] = hh;
    }
}

// ---------------- projection GEMM: [4096,512] @ [512,8000]^T(row-major W) + bias ----------------
// grid (63, 32, 2); 256 thr = 4 waves in 2x2; wave tile 64x64 = 4x4 mfma tiles.
__global__ __launch_bounds__(256)
void proj_gemm(const bf16_t* __restrict__ hA, const bf16_t* __restrict__ Wp,
               const float* __restrict__ b_fwd, const float* __restrict__ b_bwd,
               float* __restrict__ out)
{
    const int d  = blockIdx.z;
    const int n0 = blockIdx.x * 128;
    const int m0 = blockIdx.y * 128;
    const bf16_t* A  = hA + (size_t)d * (SS * BB * HH);
    const bf16_t* Bw = Wp + (size_t)d * ((size_t)VPAD * HH);
    const float* bias = d ? b_bwd : b_fwd;
    float* O = out + (size_t)d * ((size_t)SS * BB * VV);

    __shared__ __align__(16) bf16_t lds_a[128 * 32];
    __shared__ __align__(16) bf16_t lds_b[128 * 32];

    const int tid  = threadIdx.x;
    const int lane = tid & 63;
    const int wv   = tid >> 6;
    const int wm   = wv >> 1, wn = wv & 1;
    const int lrow = lane & 15, quad = lane >> 4;

    floatx4 acc[4][4];
#pragma unroll
    for (int i = 0; i < 4; ++i)
#pragma unroll
        for (int j = 0; j < 4; ++j) acc[i][j] = (floatx4){0.f, 0.f, 0.f, 0.f};

    for (int k0 = 0; k0 < HH; k0 += 32) {
        __syncthreads();
#pragma unroll
        for (int q2 = 0; q2 < 2; ++q2) {
            int q = tid * 2 + q2;           // 0..511
            int row = q >> 2, cc = (q & 3) * 8;
            *(bf16x8*)(&lds_a[row * 32 + cc]) = *(const bf16x8*)(A  + (size_t)(m0 + row) * HH + k0 + cc);
            *(bf16x8*)(&lds_b[row * 32 + cc]) = *(const bf16x8*)(Bw + (size_t)(n0 + row) * HH + k0 + cc);
        }
        __syncthreads();
        bf16x8 af[4], bf4[4];
#pragma unroll
        for (int i = 0; i < 4; ++i) {
            af[i]  = *(const bf16x8*)(&lds_a[(wm * 64 + i * 16 + lrow) * 32 + quad * 8]);
            bf4[i] = *(const bf16x8*)(&lds_b[(wn * 64 + i * 16 + lrow) * 32 + quad * 8]);
        }
#pragma unroll
        for (int i = 0; i < 4; ++i)
#pragma unroll
            for (int j = 0; j < 4; ++j)
                acc[i][j] = __builtin_amdgcn_mfma_f32_16x16x32_bf16(af[i], bf4[j], acc[i][j], 0, 0, 0);
    }

#pragma unroll
    for (int j = 0; j < 4; ++j) {
        int n = n0 + wn * 64 + j * 16 + lrow;
        if (n < VV) {
            float bv = bias[n];
#pragma unroll
            for (int i = 0; i < 4; ++i) {
                int mbase = m0 + wm * 64 + i * 16 + quad * 4;
#pragma unroll
                for (int rg = 0; rg < 4; ++rg)
                    O[(size_t)(mbase + rg) * VV + n] = acc[i][j][rg] + bv;
            }
        }
    }
}

// ---------------- launch ----------------

extern "C" void kernel_launch(void* const* d_in, const int* in_sizes, int n_in,
                              void* d_out, int out_size, void* d_ws, size_t ws_size,
                              hipStream_t stream)
{
    const float* x     = (const float*)d_in[0];
    const float* Wf_ih = (const float*)d_in[1];
    const float* Wf_hh = (const float*)d_in[2];
    const float* bf_ih = (const float*)d_in[3];
    const float* bf_hh = (const float*)d_in[4];
    const float* Wb_ih = (const float*)d_in[5];
    const float* Wb_hh = (const float*)d_in[6];
    const float* bb_ih = (const float*)d_in[7];
    const float* bb_hh = (const float*)d_in[8];
    const float* W_fwd = (const float*)d_in[9];
    const float* b_fwd = (const float*)d_in[10];
    const float* W_bwd = (const float*)d_in[11];
    const float* b_bwd = (const float*)d_in[12];
    float* out = (float*)d_out;

    // workspace layout (bytes), ~67.6 MB total
    char* ws = (char*)d_ws;
    bf16_t* h_hi = (bf16_t*)(ws + 0);          // [2d][2l][2ph][32][512] bf16 = 256KB
    bf16_t* h_lo = (bf16_t*)(ws + 262144);     // 256KB
    float*  c_st = (float*) (ws + 524288);     // [2d][2l][32][512] f32 = 256KB
    bf16_t* x_hi = (bf16_t*)(ws + 786432);     // [128][32][512] bf16 = 4MB
    bf16_t* x_lo = (bf16_t*)(ws + 4980736);    // 4MB
    bf16_t* Wch  = (bf16_t*)(ws + 9175040);    // [2][2][2048][1024] bf16 = 16MB
    bf16_t* Wcl  = (bf16_t*)(ws + 25952256);   // 16MB
    bf16_t* hout = (bf16_t*)(ws + 42729472);   // [2][128][32][512] bf16 = 8MB
    bf16_t* Wp   = (bf16_t*)(ws + 51118080);   // [2][8064][512] bf16 = 15.75MB

    // zero initial h (both phases, hi+lo) and c
    hipMemsetAsync(d_ws, 0, 786432, stream);

    prep_x <<<dim3(2097152 / 256), 256, 0, stream>>>(x, x_hi, x_lo);
    prep_w <<<dim3(8388608 / 256), 256, 0, stream>>>(Wf_ih, Wf_hh, Wb_ih, Wb_hh, Wch, Wcl);
    prep_wp<<<dim3(8257536 / 256), 256, 0, stream>>>(W_fwd, W_bwd, Wp);

    for (int r = 0; r <= SS; ++r)
        lstm_round<<<dim3(32, 2, 2), 512, 0, stream>>>(
            x_hi, x_lo, Wch, Wcl, bf_ih, bf_hh, bb_ih, bb_hh, h_hi, h_lo, c_st, hout, r);

    proj_gemm<<<dim3(63, 32, 2), 256, 0, stream>>>(hout, Wp, b_fwd, b_bwd, out);
}

// Round 2
// 3314.771 us; speedup vs baseline: 1.0946x; 1.0946x over previous
//
#include <hip/hip_runtime.h>

#define SS 128
#define BB 32
#define HH 512
#define VV 8000
#define VPAD 8064

typedef __bf16 bf16_t;
typedef __bf16 bf16x8 __attribute__((ext_vector_type(8)));
typedef float  floatx4 __attribute__((ext_vector_type(4)));

__device__ __forceinline__ float sigmoidf_(float x) { return 1.0f / (1.0f + expf(-x)); }

// ---------------- workspace layout (bytes) ----------------
#define WS_CNT   0                       // 4 ints (group arrival counters)
#define WS_HHI   256                     // h ring hi [2d][2l][4 slot][32][512] bf16 = 524288
#define WS_HLO   (WS_HHI + 524288)       // h ring lo = 524288
#define WS_CST   (WS_HLO + 524288)       // c state [2d][2l][32][512] f32 = 262144
#define WS_XHI   (WS_CST + 262144)       // x hi [128][32][512] bf16 = 4194304
#define WS_XLO   (WS_XHI + 4194304)      // x lo = 4194304
#define WS_HOUT  (WS_XLO + 4194304)      // top-layer h [2][128][32][512] bf16 = 8388608
#define WS_WP    (WS_HOUT + 8388608)     // proj weights [2][8064][512] bf16 = 16515072
#define MEMSET_BYTES WS_XHI              // zero counters + h ring + c

// LDS: weights 131072 + pbuf 4*32*33*4 = 16896 + bsum 128  -> 148224 (<160 KiB)
#define SMEM_BYTES 148224

// ---------------- prep kernels ----------------

__global__ __launch_bounds__(256)
void prep_x(const float* __restrict__ x, bf16_t* __restrict__ xh, bf16_t* __restrict__ xl) {
    int i = blockIdx.x * 256 + threadIdx.x;   // 128*32*512 = 2097152 exact
    float v = x[i];
    bf16_t h = (bf16_t)v;
    xh[i] = h;
    xl[i] = (bf16_t)(v - (float)h);
}

__global__ __launch_bounds__(256)
void prep_wp(const float* __restrict__ Wf, const float* __restrict__ Wb, bf16_t* __restrict__ Wp) {
    int i = blockIdx.x * 256 + threadIdx.x;   // 2*8064*512 = 8257536 exact
    int k   = i & 511;
    int rd  = i >> 9;
    int row = rd % 8064;
    int d   = rd / 8064;
    const float* W = d ? Wb : Wf;
    Wp[i] = (row < VV) ? (bf16_t)W[(size_t)row * 512 + k] : (bf16_t)0.0f;
}

// ---------------- persistent LSTM ----------------
// 256 WGs x 512 thr, 1 WG/CU. WG = (d, l, s): 8 h-cols x 4 gates of one (dir,layer).
// Weights (split hi/lo) live in LDS in pre-swizzled MFMA fragment order.
// Wave kq (0..7): half = kq>>2 (0: input A, 1: recurrent A), kb = kq&3 (128-k block).
// Fine-grained group barriers: counter per (d,l) group of 64 WGs.

__device__ __forceinline__ void wait_ge(int* p, int tgt) {
    while (__hip_atomic_load(p, __ATOMIC_RELAXED, __HIP_MEMORY_SCOPE_AGENT) < tgt)
        __builtin_amdgcn_s_sleep(1);
}

__global__ __launch_bounds__(512, 2)
void lstm_persist(const float* __restrict__ Wf_ih, const float* __restrict__ Wf_hh,
                  const float* __restrict__ Wb_ih, const float* __restrict__ Wb_hh,
                  const float* __restrict__ bf_ih, const float* __restrict__ bf_hh,
                  const float* __restrict__ bb_ih, const float* __restrict__ bb_hh,
                  const bf16_t* __restrict__ x_hi, const bf16_t* __restrict__ x_lo,
                  bf16_t* __restrict__ h_hi, bf16_t* __restrict__ h_lo,
                  float* __restrict__ c_st, bf16_t* __restrict__ hout,
                  int* __restrict__ cnt)
{
    extern __shared__ char smem[];
    bf16_t* wlds = (bf16_t*)smem;                     // 128 KB weight fragments
    float*  pbuf = (float*)(smem + 131072);           // [4][32][33] k-partials
    float*  bsum = (float*)(smem + 131072 + 16896);   // [32] combined bias

    const int bid  = blockIdx.x;
    const int d    = bid >> 7;
    const int l    = (bid >> 6) & 1;
    const int s    = bid & 63;
    const int gid  = d * 2 + l;
    const int tid  = threadIdx.x;
    const int lane = tid & 63;
    const int kq   = tid >> 6;
    const int half = kq >> 2;
    const int kb   = kq & 3;
    const int lrow = lane & 15;
    const int quad = lane >> 4;

    const float* Wih = (d ? Wb_ih : Wf_ih) + (size_t)l * (2048 * 512);
    const float* Whh = (d ? Wb_hh : Wf_hh) + (size_t)l * (2048 * 512);

    if (tid < 32) {
        int g = tid >> 3, c = tid & 7;
        int grow = g * 512 + s * 8 + c;
        bsum[tid] = (d ? bb_ih : bf_ih)[l * 2048 + grow] + (d ? bb_hh : bf_hh)[l * 2048 + grow];
    }

    // one-time weight fill: each wave writes exactly the fragments it will read.
    // chunk = ((kq*4 + j)*2 + nt)*2 + t ; within chunk: lane*16B = B-frag for that lane.
    {
        const float* Wsrc = half ? Whh : Wih;
        bf16x8* w8 = (bf16x8*)wlds;
#pragma unroll
        for (int j = 0; j < 4; ++j)
#pragma unroll
            for (int nt = 0; nt < 2; ++nt) {
                int n    = nt * 16 + lrow;
                int grow = (n >> 3) * 512 + s * 8 + (n & 7);
                const float* src = Wsrc + (size_t)grow * 512 + (kb * 128 + j * 32 + quad * 8);
                bf16x8 vh, vl;
#pragma unroll
                for (int e = 0; e < 8; ++e) {
                    float v = src[e];
                    bf16_t hb = (bf16_t)v;
                    vh[e] = hb;
                    vl[e] = (bf16_t)(v - (float)hb);
                }
                int cidx = ((kq * 4 + j) * 2 + nt) * 2;
                w8[(size_t)cidx * 64 + lane]       = vh;
                w8[(size_t)(cidx + 1) * 64 + lane] = vl;
            }
    }
    __syncthreads();

    const bf16x8* wv8 = (const bf16x8*)wlds + (size_t)kq * 1024 + lane;
    const int aoff = lrow * 512 + kb * 128 + quad * 8;

#pragma unroll 1
    for (int t = 0; t < SS; ++t) {
        // ---- gates ----
        if (tid == 0) {
            if (l == 0) {
                wait_ge(&cnt[gid], t * 64);                      // own group done t-1
                if (t >= 4) wait_ge(&cnt[gid + 1], (t - 3) * 64); // L1 read h0 ring slot
            } else {
                wait_ge(&cnt[gid - 1], (t + 1) * 64);            // h0(t) available
                wait_ge(&cnt[gid], t * 64);                      // own h1(t-1)
            }
            __builtin_amdgcn_fence(__ATOMIC_ACQUIRE, "agent");
        }
        __syncthreads();

        const int slot_c = t & 3, slot_p = (t + 3) & 3;
        const bf16_t *pAh, *pAl;
        if (half == 0) {
            if (l == 0) {
                int t_x = d ? (SS - 1 - t) : t;
                pAh = x_hi + (size_t)t_x * 16384;
                pAl = x_lo + (size_t)t_x * 16384;
            } else {
                pAh = h_hi + (size_t)((d * 2 + 0) * 4 + slot_c) * 16384;
                pAl = h_lo + (size_t)((d * 2 + 0) * 4 + slot_c) * 16384;
            }
        } else {
            pAh = h_hi + (size_t)(gid * 4 + slot_p) * 16384;
            pAl = h_lo + (size_t)(gid * 4 + slot_p) * 16384;
        }
        const bf16_t* ah = pAh + aoff;
        const bf16_t* al = pAl + aoff;

        floatx4 acc00 = {0,0,0,0}, acc01 = {0,0,0,0}, acc10 = {0,0,0,0}, acc11 = {0,0,0,0};
#pragma unroll
        for (int j = 0; j < 4; ++j) {
            const int ko = j * 32;
            bf16x8 ah0 = *(const bf16x8*)(ah + ko);
            bf16x8 ah1 = *(const bf16x8*)(ah + 8192 + ko);
            bf16x8 al0 = *(const bf16x8*)(al + ko);
            bf16x8 al1 = *(const bf16x8*)(al + 8192 + ko);
            bf16x8 b0h = wv8[j * 256];
            bf16x8 b0l = wv8[j * 256 + 64];
            bf16x8 b1h = wv8[j * 256 + 128];
            bf16x8 b1l = wv8[j * 256 + 192];
            acc00 = __builtin_amdgcn_mfma_f32_16x16x32_bf16(ah0, b0h, acc00, 0, 0, 0);
            acc00 = __builtin_amdgcn_mfma_f32_16x16x32_bf16(ah0, b0l, acc00, 0, 0, 0);
            acc00 = __builtin_amdgcn_mfma_f32_16x16x32_bf16(al0, b0h, acc00, 0, 0, 0);
            acc01 = __builtin_amdgcn_mfma_f32_16x16x32_bf16(ah0, b1h, acc01, 0, 0, 0);
            acc01 = __builtin_amdgcn_mfma_f32_16x16x32_bf16(ah0, b1l, acc01, 0, 0, 0);
            acc01 = __builtin_amdgcn_mfma_f32_16x16x32_bf16(al0, b1h, acc01, 0, 0, 0);
            acc10 = __builtin_amdgcn_mfma_f32_16x16x32_bf16(ah1, b0h, acc10, 0, 0, 0);
            acc10 = __builtin_amdgcn_mfma_f32_16x16x32_bf16(ah1, b0l, acc10, 0, 0, 0);
            acc10 = __builtin_amdgcn_mfma_f32_16x16x32_bf16(al1, b0h, acc10, 0, 0, 0);
            acc11 = __builtin_amdgcn_mfma_f32_16x16x32_bf16(ah1, b1h, acc11, 0, 0, 0);
            acc11 = __builtin_amdgcn_mfma_f32_16x16x32_bf16(ah1, b1l, acc11, 0, 0, 0);
            acc11 = __builtin_amdgcn_mfma_f32_16x16x32_bf16(al1, b1h, acc11, 0, 0, 0);
        }

        // ---- k-partial reduce: input waves store, recurrent waves add ----
        if (half == 0) {
#pragma unroll
            for (int rg = 0; rg < 4; ++rg) {
                pbuf[kb * 1056 + (quad * 4 + rg) * 33 + lrow]           = acc00[rg];
                pbuf[kb * 1056 + (quad * 4 + rg) * 33 + 16 + lrow]      = acc01[rg];
                pbuf[kb * 1056 + (16 + quad * 4 + rg) * 33 + lrow]      = acc10[rg];
                pbuf[kb * 1056 + (16 + quad * 4 + rg) * 33 + 16 + lrow] = acc11[rg];
            }
        }
        __syncthreads();
        if (half == 1) {
#pragma unroll
            for (int rg = 0; rg < 4; ++rg) {
                pbuf[kb * 1056 + (quad * 4 + rg) * 33 + lrow]           += acc00[rg];
                pbuf[kb * 1056 + (quad * 4 + rg) * 33 + 16 + lrow]      += acc01[rg];
                pbuf[kb * 1056 + (16 + quad * 4 + rg) * 33 + lrow]      += acc10[rg];
                pbuf[kb * 1056 + (16 + quad * 4 + rg) * 33 + 16 + lrow] += acc11[rg];
            }
        }
        __syncthreads();

        // ---- epilogue: 256 threads, one (batch, col) each ----
        if (tid < 256) {
            int b = tid >> 3, c = tid & 7;
            float gi = 0.f, gf = 0.f, gg = 0.f, go = 0.f;
#pragma unroll
            for (int kbb = 0; kbb < 4; ++kbb) {
                int base = kbb * 1056 + b * 33 + c;
                gi += pbuf[base];
                gf += pbuf[base + 8];
                gg += pbuf[base + 16];
                go += pbuf[base + 24];
            }
            gi += bsum[c]; gf += bsum[8 + c]; gg += bsum[16 + c]; go += bsum[24 + c];
            int col = s * 8 + c;
            float* cp = c_st + ((size_t)gid * BB + b) * HH + col;
            float cold = *cp;
            float cn = sigmoidf_(gf) * cold + sigmoidf_(gi) * tanhf(gg);
            float hn = sigmoidf_(go) * tanhf(cn);
            *cp = cn;
            bf16_t hh = (bf16_t)hn;
            bf16_t hl = (bf16_t)(hn - (float)hh);
            size_t ho = (size_t)(gid * 4 + slot_c) * 16384 + (size_t)b * HH + col;
            h_hi[ho] = hh;
            h_lo[ho] = hl;
            if (l == 1) {
                int t_x = d ? (SS - 1 - t) : t;
                hout[((size_t)(d * SS + t_x) * BB + b) * HH + col] = hh;
            }
        }

        // ---- arrive ----
        __syncthreads();   // drains all waves' stores (vmcnt0 before s_barrier)
        if (tid == 0) {
            __builtin_amdgcn_fence(__ATOMIC_RELEASE, "agent");
            __hip_atomic_fetch_add(&cnt[gid], 1, __ATOMIC_RELAXED, __HIP_MEMORY_SCOPE_AGENT);
        }
    }
}

// ---------------- projection GEMM ----------------
// [4096,512] @ W^T [512,8064] + bias, per dir. Block swizzle: bid%8 pins an
// n-block (XCD-stable B tile), sweeps m. LDS stride 40 kills bank conflicts.
__global__ __launch_bounds__(256)
void proj_gemm(const bf16_t* __restrict__ hA, const bf16_t* __restrict__ Wp,
               const float* __restrict__ b_fwd, const float* __restrict__ b_bwd,
               float* __restrict__ out)
{
    const int bid = blockIdx.x;
    const int nb  = (bid & 7) + ((bid >> 8) << 3);
    const int mb  = (bid >> 3) & 31;
    if (nb >= 63) return;
    const int d  = blockIdx.z;
    const int n0 = nb * 128;
    const int m0 = mb * 128;
    const bf16_t* A  = hA + (size_t)d * (SS * BB * HH);
    const bf16_t* Bw = Wp + (size_t)d * ((size_t)VPAD * HH);
    const float* bias = d ? b_bwd : b_fwd;
    float* O = out + (size_t)d * ((size_t)SS * BB * VV);

    __shared__ __align__(16) bf16_t lds_a[128 * 40];
    __shared__ __align__(16) bf16_t lds_b[128 * 40];

    const int tid  = threadIdx.x;
    const int lane = tid & 63;
    const int wv   = tid >> 6;
    const int wm   = wv >> 1, wn = wv & 1;
    const int lrow = lane & 15, quad = lane >> 4;

    floatx4 acc[4][4];
#pragma unroll
    for (int i = 0; i < 4; ++i)
#pragma unroll
        for (int j = 0; j < 4; ++j) acc[i][j] = (floatx4){0.f, 0.f, 0.f, 0.f};

    for (int k0 = 0; k0 < HH; k0 += 32) {
        __syncthreads();
#pragma unroll
        for (int q2 = 0; q2 < 2; ++q2) {
            int q = tid * 2 + q2;
            int row = q >> 2, cc = (q & 3) * 8;
            *(bf16x8*)(&lds_a[row * 40 + cc]) = *(const bf16x8*)(A  + (size_t)(m0 + row) * HH + k0 + cc);
            *(bf16x8*)(&lds_b[row * 40 + cc]) = *(const bf16x8*)(Bw + (size_t)(n0 + row) * HH + k0 + cc);
        }
        __syncthreads();
        bf16x8 af[4], bf4[4];
#pragma unroll
        for (int i = 0; i < 4; ++i) {
            af[i]  = *(const bf16x8*)(&lds_a[(wm * 64 + i * 16 + lrow) * 40 + quad * 8]);
            bf4[i] = *(const bf16x8*)(&lds_b[(wn * 64 + i * 16 + lrow) * 40 + quad * 8]);
        }
#pragma unroll
        for (int i = 0; i < 4; ++i)
#pragma unroll
            for (int j = 0; j < 4; ++j)
                acc[i][j] = __builtin_amdgcn_mfma_f32_16x16x32_bf16(af[i], bf4[j], acc[i][j], 0, 0, 0);
    }

#pragma unroll
    for (int j = 0; j < 4; ++j) {
        int n = n0 + wn * 64 + j * 16 + lrow;
        if (n < VV) {
            float bv = bias[n];
#pragma unroll
            for (int i = 0; i < 4; ++i) {
                int mbase = m0 + wm * 64 + i * 16 + quad * 4;
#pragma unroll
                for (int rg = 0; rg < 4; ++rg)
                    O[(size_t)(mbase + rg) * VV + n] = acc[i][j][rg] + bv;
            }
        }
    }
}

// ---------------- launch ----------------

extern "C" void kernel_launch(void* const* d_in, const int* in_sizes, int n_in,
                              void* d_out, int out_size, void* d_ws, size_t ws_size,
                              hipStream_t stream)
{
    const float* x     = (const float*)d_in[0];
    const float* Wf_ih = (const float*)d_in[1];
    const float* Wf_hh = (const float*)d_in[2];
    const float* bf_ih = (const float*)d_in[3];
    const float* bf_hh = (const float*)d_in[4];
    const float* Wb_ih = (const float*)d_in[5];
    const float* Wb_hh = (const float*)d_in[6];
    const float* bb_ih = (const float*)d_in[7];
    const float* bb_hh = (const float*)d_in[8];
    const float* W_fwd = (const float*)d_in[9];
    const float* b_fwd = (const float*)d_in[10];
    const float* W_bwd = (const float*)d_in[11];
    const float* b_bwd = (const float*)d_in[12];
    float* out = (float*)d_out;
    (void)in_sizes; (void)n_in; (void)out_size; (void)ws_size;

    char* ws = (char*)d_ws;
    int*    cnt  = (int*)   (ws + WS_CNT);
    bf16_t* h_hi = (bf16_t*)(ws + WS_HHI);
    bf16_t* h_lo = (bf16_t*)(ws + WS_HLO);
    float*  c_st = (float*) (ws + WS_CST);
    bf16_t* x_hi = (bf16_t*)(ws + WS_XHI);
    bf16_t* x_lo = (bf16_t*)(ws + WS_XLO);
    bf16_t* hout = (bf16_t*)(ws + WS_HOUT);
    bf16_t* Wp   = (bf16_t*)(ws + WS_WP);

    (void)hipFuncSetAttribute(reinterpret_cast<const void*>(lstm_persist),
                              hipFuncAttributeMaxDynamicSharedMemorySize, SMEM_BYTES);

    hipMemsetAsync(ws, 0, MEMSET_BYTES, stream);

    prep_x <<<dim3(8192),  256, 0, stream>>>(x, x_hi, x_lo);
    prep_wp<<<dim3(32256), 256, 0, stream>>>(W_fwd, W_bwd, Wp);

    lstm_persist<<<dim3(256), dim3(512), SMEM_BYTES, stream>>>(
        Wf_ih, Wf_hh, Wb_ih, Wb_hh, bf_ih, bf_hh, bb_ih, bb_hh,
        x_hi, x_lo, h_hi, h_lo, c_st, hout, cnt);

    proj_gemm<<<dim3(2048, 1, 2), 256, 0, stream>>>(hout, Wp, b_fwd, b_bwd, out);
}

// Round 3
// 2452.008 us; speedup vs baseline: 1.4797x; 1.3519x over previous
//
#include <hip/hip_runtime.h>

#define SS 128
#define BB 32
#define HH 512
#define VV 8000
#define VPAD 8064

typedef __bf16 bf16_t;
typedef __bf16 bf16x8 __attribute__((ext_vector_type(8)));
typedef float  floatx4 __attribute__((ext_vector_type(4)));

__device__ __forceinline__ float sigmoidf_(float x) { return 1.0f / (1.0f + expf(-x)); }

// ---------------- workspace layout (bytes) ----------------
#define WS_FLG   0                       // flags[4][64] int = 1024 B (per-WG "steps done")
#define WS_HHI   1024                    // h ring hi [2d][2l][4 slot][32][512] bf16 = 524288
#define WS_HLO   (WS_HHI + 524288)       // h ring lo = 524288
#define WS_XHI   (WS_HLO + 524288)       // x hi [128][32][512] bf16 = 4194304
#define WS_XLO   (WS_XHI + 4194304)      // x lo = 4194304
#define WS_HOUT  (WS_XLO + 4194304)      // top-layer h [2][128][32][512] bf16 = 8388608
#define WS_WP    (WS_HOUT + 8388608)     // proj weights [2][8064][512] bf16 = 16515072
#define MEMSET_BYTES WS_XHI              // zero flags + h ring

// LDS: weights 131072 + pbuf 4*32*36*4 = 18432 + bsum 128 -> 149632 (< 160 KiB)
#define SMEM_BYTES 149632

// ---------------- prep kernels ----------------

__global__ __launch_bounds__(256)
void prep_x(const float* __restrict__ x, bf16_t* __restrict__ xh, bf16_t* __restrict__ xl) {
    int i = blockIdx.x * 256 + threadIdx.x;   // 128*32*512 = 2097152 exact
    float v = x[i];
    bf16_t h = (bf16_t)v;
    xh[i] = h;
    xl[i] = (bf16_t)(v - (float)h);
}

__global__ __launch_bounds__(256)
void prep_wp(const float* __restrict__ Wf, const float* __restrict__ Wb, bf16_t* __restrict__ Wp) {
    int i = blockIdx.x * 256 + threadIdx.x;   // 2*8064*512 = 8257536 exact
    int k   = i & 511;
    int rd  = i >> 9;
    int row = rd % 8064;
    int d   = rd / 8064;
    const float* W = d ? Wb : Wf;
    Wp[i] = (row < VV) ? (bf16_t)W[(size_t)row * 512 + k] : (bf16_t)0.0f;
}

// ---------------- persistent LSTM ----------------
// 256 WGs x 512 thr, 1 WG/CU. WG = (d, l, s): 8 h-cols x 4 gates of one (dir,layer).
// Weights (split hi/lo) in LDS, pre-swizzled MFMA fragment order.
// Wave kq (0..7): half = kq>>2 (0: input A, 1: recurrent A), kb = kq&3 (128-k block).
// Sync: per-WG completion flags (plain release stores, NO atomicRMW);
// waiters poll 64 flags with one coalesced 64-lane load + __all().

__global__ __launch_bounds__(512, 2)
void lstm_persist(const float* __restrict__ Wf_ih, const float* __restrict__ Wf_hh,
                  const float* __restrict__ Wb_ih, const float* __restrict__ Wb_hh,
                  const float* __restrict__ bf_ih, const float* __restrict__ bf_hh,
                  const float* __restrict__ bb_ih, const float* __restrict__ bb_hh,
                  const bf16_t* __restrict__ x_hi, const bf16_t* __restrict__ x_lo,
                  bf16_t* __restrict__ h_hi, bf16_t* __restrict__ h_lo,
                  bf16_t* __restrict__ hout, int* __restrict__ flg)
{
    extern __shared__ char smem[];
    bf16_t* wlds = (bf16_t*)smem;                     // 128 KB weight fragments
    float*  pbuf = (float*)(smem + 131072);           // [4 kb][32 row][36] k-partials
    float*  bsum = (float*)(smem + 131072 + 18432);   // [32] combined bias

    const int bid  = blockIdx.x;
    const int d    = bid >> 7;
    const int l    = (bid >> 6) & 1;
    const int s    = bid & 63;
    const int gid  = d * 2 + l;
    const int tid  = threadIdx.x;
    const int lane = tid & 63;
    const int kq   = tid >> 6;
    const int half = kq >> 2;
    const int kb   = kq & 3;
    const int lrow = lane & 15;
    const int quad = lane >> 4;

    const float* Wih = (d ? Wb_ih : Wf_ih) + (size_t)l * (2048 * 512);
    const float* Whh = (d ? Wb_hh : Wf_hh) + (size_t)l * (2048 * 512);

    if (tid < 32) {
        int g = tid >> 3, c = tid & 7;
        int grow = g * 512 + s * 8 + c;
        bsum[tid] = (d ? bb_ih : bf_ih)[l * 2048 + grow] + (d ? bb_hh : bf_hh)[l * 2048 + grow];
    }

    // one-time weight fill: each wave writes exactly the fragments it will read.
    {
        const float* Wsrc = half ? Whh : Wih;
        bf16x8* w8 = (bf16x8*)wlds;
#pragma unroll
        for (int j = 0; j < 4; ++j)
#pragma unroll
            for (int nt = 0; nt < 2; ++nt) {
                int n    = nt * 16 + lrow;
                int grow = (n >> 3) * 512 + s * 8 + (n & 7);
                const float* src = Wsrc + (size_t)grow * 512 + (kb * 128 + j * 32 + quad * 8);
                bf16x8 vh, vl;
#pragma unroll
                for (int e = 0; e < 8; ++e) {
                    float v = src[e];
                    bf16_t hb = (bf16_t)v;
                    vh[e] = hb;
                    vl[e] = (bf16_t)(v - (float)hb);
                }
                int cidx = ((kq * 4 + j) * 2 + nt) * 2;
                w8[(size_t)cidx * 64 + lane]       = vh;
                w8[(size_t)(cidx + 1) * 64 + lane] = vl;
            }
    }
    __syncthreads();

    const bf16x8* wv8 = (const bf16x8*)wlds + (size_t)kq * 1024 + lane;
    const int aoff = lrow * 512 + kb * 128 + quad * 8;

    // persistent cell state: epilogue thread (tid<256) owns (b = tid>>3, c = tid&7)
    float creg = 0.0f;

#pragma unroll 1
    for (int t = 0; t < SS; ++t) {
        // ---- wait for dependencies (wave 0 polls 64 flags/lane-parallel) ----
        if (tid < 64) {
            const int *fA, *fB; int tA, tB;
            if (l == 0) { fA = flg + gid * 64;       tA = t;
                          fB = flg + (gid + 1) * 64; tB = t - 3; }   // ring guard
            else        { fA = flg + (gid - 1) * 64; tA = t + 1;     // h0(t) ready
                          fB = flg + gid * 64;       tB = t; }
            for (;;) {
                int a = __hip_atomic_load(fA + tid, __ATOMIC_RELAXED, __HIP_MEMORY_SCOPE_AGENT);
                int b = __hip_atomic_load(fB + tid, __ATOMIC_RELAXED, __HIP_MEMORY_SCOPE_AGENT);
                if (__all((a >= tA) && (b >= tB))) break;
                __builtin_amdgcn_s_sleep(2);
            }
            if (tid == 0) __builtin_amdgcn_fence(__ATOMIC_ACQUIRE, "agent");
        }
        __syncthreads();

        const int slot_c = t & 3, slot_p = (t + 3) & 3;
        const bf16_t *pAh, *pAl;
        if (half == 0) {
            if (l == 0) {
                int t_x = d ? (SS - 1 - t) : t;
                pAh = x_hi + (size_t)t_x * 16384;
                pAl = x_lo + (size_t)t_x * 16384;
            } else {
                pAh = h_hi + (size_t)((d * 2 + 0) * 4 + slot_c) * 16384;
                pAl = h_lo + (size_t)((d * 2 + 0) * 4 + slot_c) * 16384;
            }
        } else {
            pAh = h_hi + (size_t)(gid * 4 + slot_p) * 16384;
            pAl = h_lo + (size_t)(gid * 4 + slot_p) * 16384;
        }
        const bf16_t* ah = pAh + aoff;
        const bf16_t* al = pAl + aoff;

        floatx4 acc00 = {0,0,0,0}, acc01 = {0,0,0,0}, acc10 = {0,0,0,0}, acc11 = {0,0,0,0};
#pragma unroll
        for (int j = 0; j < 4; ++j) {
            const int ko = j * 32;
            bf16x8 ah0 = *(const bf16x8*)(ah + ko);
            bf16x8 ah1 = *(const bf16x8*)(ah + 8192 + ko);
            bf16x8 al0 = *(const bf16x8*)(al + ko);
            bf16x8 al1 = *(const bf16x8*)(al + 8192 + ko);
            bf16x8 b0h = wv8[j * 256];
            bf16x8 b0l = wv8[j * 256 + 64];
            bf16x8 b1h = wv8[j * 256 + 128];
            bf16x8 b1l = wv8[j * 256 + 192];
            acc00 = __builtin_amdgcn_mfma_f32_16x16x32_bf16(ah0, b0h, acc00, 0, 0, 0);
            acc00 = __builtin_amdgcn_mfma_f32_16x16x32_bf16(ah0, b0l, acc00, 0, 0, 0);
            acc00 = __builtin_amdgcn_mfma_f32_16x16x32_bf16(al0, b0h, acc00, 0, 0, 0);
            acc01 = __builtin_amdgcn_mfma_f32_16x16x32_bf16(ah0, b1h, acc01, 0, 0, 0);
            acc01 = __builtin_amdgcn_mfma_f32_16x16x32_bf16(ah0, b1l, acc01, 0, 0, 0);
            acc01 = __builtin_amdgcn_mfma_f32_16x16x32_bf16(al0, b1h, acc01, 0, 0, 0);
            acc10 = __builtin_amdgcn_mfma_f32_16x16x32_bf16(ah1, b0h, acc10, 0, 0, 0);
            acc10 = __builtin_amdgcn_mfma_f32_16x16x32_bf16(ah1, b0l, acc10, 0, 0, 0);
            acc10 = __builtin_amdgcn_mfma_f32_16x16x32_bf16(al1, b0h, acc10, 0, 0, 0);
            acc11 = __builtin_amdgcn_mfma_f32_16x16x32_bf16(ah1, b1h, acc11, 0, 0, 0);
            acc11 = __builtin_amdgcn_mfma_f32_16x16x32_bf16(ah1, b1l, acc11, 0, 0, 0);
            acc11 = __builtin_amdgcn_mfma_f32_16x16x32_bf16(al1, b1h, acc11, 0, 0, 0);
        }

        // ---- k-partial reduce (stride 36: bank-conflict-free 2-way) ----
        if (half == 0) {
#pragma unroll
            for (int rg = 0; rg < 4; ++rg) {
                pbuf[kb * 1152 + (quad * 4 + rg) * 36 + lrow]           = acc00[rg];
                pbuf[kb * 1152 + (quad * 4 + rg) * 36 + 16 + lrow]      = acc01[rg];
                pbuf[kb * 1152 + (16 + quad * 4 + rg) * 36 + lrow]      = acc10[rg];
                pbuf[kb * 1152 + (16 + quad * 4 + rg) * 36 + 16 + lrow] = acc11[rg];
            }
        }
        __syncthreads();
        if (half == 1) {
#pragma unroll
            for (int rg = 0; rg < 4; ++rg) {
                pbuf[kb * 1152 + (quad * 4 + rg) * 36 + lrow]           += acc00[rg];
                pbuf[kb * 1152 + (quad * 4 + rg) * 36 + 16 + lrow]      += acc01[rg];
                pbuf[kb * 1152 + (16 + quad * 4 + rg) * 36 + lrow]      += acc10[rg];
                pbuf[kb * 1152 + (16 + quad * 4 + rg) * 36 + 16 + lrow] += acc11[rg];
            }
        }
        __syncthreads();

        // ---- epilogue: 256 threads, one (batch, col) each; c in register ----
        if (tid < 256) {
            int b = tid >> 3, c = tid & 7;
            float gi = 0.f, gf = 0.f, gg = 0.f, go = 0.f;
#pragma unroll
            for (int kbb = 0; kbb < 4; ++kbb) {
                int base = kbb * 1152 + b * 36 + c;
                gi += pbuf[base];
                gf += pbuf[base + 8];
                gg += pbuf[base + 16];
                go += pbuf[base + 24];
            }
            gi += bsum[c]; gf += bsum[8 + c]; gg += bsum[16 + c]; go += bsum[24 + c];
            float cn = sigmoidf_(gf) * creg + sigmoidf_(gi) * tanhf(gg);
            float hn = sigmoidf_(go) * tanhf(cn);
            creg = cn;
            bf16_t hh = (bf16_t)hn;
            bf16_t hl = (bf16_t)(hn - (float)hh);
            int col = s * 8 + c;
            size_t ho = (size_t)(gid * 4 + slot_c) * 16384 + (size_t)b * HH + col;
            h_hi[ho] = hh;
            h_lo[ho] = hl;
            if (l == 1) {
                int t_x = d ? (SS - 1 - t) : t;
                hout[((size_t)(d * SS + t_x) * BB + b) * HH + col] = hh;
            }
        }

        // ---- arrive: release store to own flag (no RMW) ----
        __syncthreads();   // drains all waves' stores
        if (tid == 0) {
            __builtin_amdgcn_fence(__ATOMIC_RELEASE, "agent");
            __hip_atomic_store(flg + gid * 64 + s, t + 1,
                               __ATOMIC_RELAXED, __HIP_MEMORY_SCOPE_AGENT);
        }
    }
}

// ---------------- projection GEMM ----------------
__global__ __launch_bounds__(256)
void proj_gemm(const bf16_t* __restrict__ hA, const bf16_t* __restrict__ Wp,
               const float* __restrict__ b_fwd, const float* __restrict__ b_bwd,
               float* __restrict__ out)
{
    const int bid = blockIdx.x;
    const int nb  = (bid & 7) + ((bid >> 8) << 3);
    const int mb  = (bid >> 3) & 31;
    if (nb >= 63) return;
    const int d  = blockIdx.z;
    const int n0 = nb * 128;
    const int m0 = mb * 128;
    const bf16_t* A  = hA + (size_t)d * (SS * BB * HH);
    const bf16_t* Bw = Wp + (size_t)d * ((size_t)VPAD * HH);
    const float* bias = d ? b_bwd : b_fwd;
    float* O = out + (size_t)d * ((size_t)SS * BB * VV);

    __shared__ __align__(16) bf16_t lds_a[128 * 40];
    __shared__ __align__(16) bf16_t lds_b[128 * 40];

    const int tid  = threadIdx.x;
    const int lane = tid & 63;
    const int wv   = tid >> 6;
    const int wm   = wv >> 1, wn = wv & 1;
    const int lrow = lane & 15, quad = lane >> 4;

    floatx4 acc[4][4];
#pragma unroll
    for (int i = 0; i < 4; ++i)
#pragma unroll
        for (int j = 0; j < 4; ++j) acc[i][j] = (floatx4){0.f, 0.f, 0.f, 0.f};

    for (int k0 = 0; k0 < HH; k0 += 32) {
        __syncthreads();
#pragma unroll
        for (int q2 = 0; q2 < 2; ++q2) {
            int q = tid * 2 + q2;
            int row = q >> 2, cc = (q & 3) * 8;
            *(bf16x8*)(&lds_a[row * 40 + cc]) = *(const bf16x8*)(A  + (size_t)(m0 + row) * HH + k0 + cc);
            *(bf16x8*)(&lds_b[row * 40 + cc]) = *(const bf16x8*)(Bw + (size_t)(n0 + row) * HH + k0 + cc);
        }
        __syncthreads();
        bf16x8 af[4], bf4[4];
#pragma unroll
        for (int i = 0; i < 4; ++i) {
            af[i]  = *(const bf16x8*)(&lds_a[(wm * 64 + i * 16 + lrow) * 40 + quad * 8]);
            bf4[i] = *(const bf16x8*)(&lds_b[(wn * 64 + i * 16 + lrow) * 40 + quad * 8]);
        }
#pragma unroll
        for (int i = 0; i < 4; ++i)
#pragma unroll
            for (int j = 0; j < 4; ++j)
                acc[i][j] = __builtin_amdgcn_mfma_f32_16x16x32_bf16(af[i], bf4[j], acc[i][j], 0, 0, 0);
    }

#pragma unroll
    for (int j = 0; j < 4; ++j) {
        int n = n0 + wn * 64 + j * 16 + lrow;
        if (n < VV) {
            float bv = bias[n];
#pragma unroll
            for (int i = 0; i < 4; ++i) {
                int mbase = m0 + wm * 64 + i * 16 + quad * 4;
#pragma unroll
                for (int rg = 0; rg < 4; ++rg)
                    O[(size_t)(mbase + rg) * VV + n] = acc[i][j][rg] + bv;
            }
        }
    }
}

// ---------------- launch ----------------

extern "C" void kernel_launch(void* const* d_in, const int* in_sizes, int n_in,
                              void* d_out, int out_size, void* d_ws, size_t ws_size,
                              hipStream_t stream)
{
    const float* x     = (const float*)d_in[0];
    const float* Wf_ih = (const float*)d_in[1];
    const float* Wf_hh = (const float*)d_in[2];
    const float* bf_ih = (const float*)d_in[3];
    const float* bf_hh = (const float*)d_in[4];
    const float* Wb_ih = (const float*)d_in[5];
    const float* Wb_hh = (const float*)d_in[6];
    const float* bb_ih = (const float*)d_in[7];
    const float* bb_hh = (const float*)d_in[8];
    const float* W_fwd = (const float*)d_in[9];
    const float* b_fwd = (const float*)d_in[10];
    const float* W_bwd = (const float*)d_in[11];
    const float* b_bwd = (const float*)d_in[12];
    float* out = (float*)d_out;
    (void)in_sizes; (void)n_in; (void)out_size; (void)ws_size;

    char* ws = (char*)d_ws;
    int*    flg  = (int*)   (ws + WS_FLG);
    bf16_t* h_hi = (bf16_t*)(ws + WS_HHI);
    bf16_t* h_lo = (bf16_t*)(ws + WS_HLO);
    bf16_t* x_hi = (bf16_t*)(ws + WS_XHI);
    bf16_t* x_lo = (bf16_t*)(ws + WS_XLO);
    bf16_t* hout = (bf16_t*)(ws + WS_HOUT);
    bf16_t* Wp   = (bf16_t*)(ws + WS_WP);

    (void)hipFuncSetAttribute(reinterpret_cast<const void*>(lstm_persist),
                              hipFuncAttributeMaxDynamicSharedMemorySize, SMEM_BYTES);

    hipMemsetAsync(ws, 0, MEMSET_BYTES, stream);

    prep_x <<<dim3(8192),  256, 0, stream>>>(x, x_hi, x_lo);
    prep_wp<<<dim3(32256), 256, 0, stream>>>(W_fwd, W_bwd, Wp);

    lstm_persist<<<dim3(256), dim3(512), SMEM_BYTES, stream>>>(
        Wf_ih, Wf_hh, Wb_ih, Wb_hh, bf_ih, bf_hh, bb_ih, bb_hh,
        x_hi, x_lo, h_hi, h_lo, hout, flg);

    proj_gemm<<<dim3(2048, 1, 2), 256, 0, stream>>>(hout, Wp, b_fwd, b_bwd, out);
}